// Round 17
// baseline (73.620 us; speedup 1.0000x reference)
//
#include <hip/hip_runtime.h>
#include <hip/hip_bf16.h>
#include <math.h>

// Problem constants: N=128, LQ=LK=64, D=512, H=8 (head split is a no-op in the einsum).
#define DN 512          // feature dim
#define NB 128          // batch N
#define QSCALE 25.0f
#define QINVS2 (1.0f / (QSCALE * QSCALE))

typedef unsigned short ushort_t;
typedef __attribute__((ext_vector_type(8))) short bf16x8;
typedef __attribute__((ext_vector_type(4))) float f32x4;
typedef __attribute__((ext_vector_type(4))) int i32x4;

// packed fp32x4 -> bf16x4 via the compiler's v_cvt_pk_bf16_f32 path
static __device__ __forceinline__ ushort4 f4tobf4(float4 v){
  __hip_bfloat162 lo = __float22bfloat162_rn(float2{v.x, v.y});
  __hip_bfloat162 hi = __float22bfloat162_rn(float2{v.z, v.w});
  ushort4 r;
  r.x = __hip_bfloat16_raw(lo.x).x; r.y = __hip_bfloat16_raw(lo.y).x;
  r.z = __hip_bfloat16_raw(hi.x).x; r.w = __hip_bfloat16_raw(hi.y).x;
  return r;
}

// async global->LDS, 16B per lane; LDS dest is wave-uniform base + lane*16
#define GLL16(gp, lp)                                                          \
  __builtin_amdgcn_global_load_lds(                                            \
      (const __attribute__((address_space(1))) void*)(gp),                     \
      (__attribute__((address_space(3))) void*)(lp), 16, 0, 0)

#define BAR() __builtin_amdgcn_s_barrier()
#define SCHED0() __builtin_amdgcn_sched_barrier(0)
#define VMC(N)                                                                 \
  do {                                                                         \
    asm volatile("s_waitcnt vmcnt(" #N ")" ::: "memory");                      \
  } while (0)

// ---------------------------------------------------------------------------
// Projections (both Q and K in one launch). Out = X @ W^T + bias.
// r17: tile 128m x 64n, grid 1024, __launch_bounds__(256,4) -> 4 blocks/CU
// (was 2): doubles the independent barrier groups per CU so one block's MFMA
// covers another's stage/convert/drain — the mechanism that held proj at
// ~13 us. LDS 24 KiB, acc[4][2]=32 AGPR. Same swizzle (slot ^= row&7), same
// XCD grouping (all n-tiles of an m-tile on one XCD; ~2.5 MB/L2 per round).
// Epilogue quantizes to int8: round(clamp(v)*25).
__global__ __launch_bounds__(256, 4) void proj_kernel(const float* __restrict__ Xq,
                                                      const float* __restrict__ Wq,
                                                      const float* __restrict__ bq,
                                                      signed char* __restrict__ Oq,
                                                      const float* __restrict__ Xk,
                                                      const float* __restrict__ Wk,
                                                      const float* __restrict__ bk,
                                                      signed char* __restrict__ Ok) {
  const int fid = blockIdx.x;                  // 0..1023
  const int xcd = fid & 7, local = fid >> 3;   // 128 locals per XCD
  const int mt = xcd * 8 + (local & 7);        // 0..63 (m-tile of 128 rows)
  const int nt = (local >> 3) & 7;             // 0..7  (n-tile of 64 cols)
  const int zz = local >> 6;                   // 0 = Q, 1 = K

  const float* X = zz ? Xk : Xq;
  const float* W = zz ? Wk : Wq;
  const float* bias = zz ? bk : bq;
  signed char* Out = zz ? Ok : Oq;

  __shared__ __align__(16) ushort_t As[128 * 64];
  __shared__ __align__(16) ushort_t Bs[64 * 64];
  const int tid = threadIdx.x;
  const int wave = tid >> 6, lane = tid & 63;
  const int wr = wave >> 1, wc = wave & 1;     // 2M x 2N waves; wave tile 64x32
  const int m0 = mt * 128, n0 = nt * 64;
  const int arow = lane & 15, g = lane >> 4;

  f32x4 acc[4][2] = {};

  for (int kt = 0; kt < 8; ++kt) {
    const int k0 = kt * 64;
#pragma unroll
    for (int i = 0; i < 8; i++) {
      int e = i * 1024 + tid * 4;
      int r = e >> 6, c = e & 63;
      int cs = ((((c >> 3) ^ (r & 7)) << 3) | (c & 7));
      float4 va = *(const float4*)&X[(size_t)(m0 + r) * DN + k0 + c];
      *(ushort4*)&As[r * 64 + cs] = f4tobf4(va);
    }
#pragma unroll
    for (int i = 0; i < 4; i++) {
      int e = i * 1024 + tid * 4;
      int r = e >> 6, c = e & 63;
      int cs = ((((c >> 3) ^ (r & 7)) << 3) | (c & 7));
      float4 vb = *(const float4*)&W[(size_t)(n0 + r) * DN + k0 + c];
      *(ushort4*)&Bs[r * 64 + cs] = f4tobf4(vb);
    }
    __syncthreads();

    bf16x8 af[4][2], bfr[2][2];
#pragma unroll
    for (int mi = 0; mi < 4; mi++)
#pragma unroll
      for (int ks = 0; ks < 2; ks++)
        af[mi][ks] = *(const bf16x8*)&As[(wr * 64 + mi * 16 + arow) * 64 +
                                         ((((ks << 2) | g) ^ (arow & 7)) << 3)];
#pragma unroll
    for (int ni = 0; ni < 2; ni++)
#pragma unroll
      for (int ks = 0; ks < 2; ks++)
        bfr[ni][ks] = *(const bf16x8*)&Bs[(wc * 32 + ni * 16 + arow) * 64 +
                                          ((((ks << 2) | g) ^ (arow & 7)) << 3)];
#pragma unroll
    for (int ks = 0; ks < 2; ks++)
#pragma unroll
      for (int mi = 0; mi < 4; mi++)
#pragma unroll
        for (int ni = 0; ni < 2; ni++)
          acc[mi][ni] = __builtin_amdgcn_mfma_f32_16x16x32_bf16(
              af[mi][ks], bfr[ni][ks], acc[mi][ni], 0, 0, 0);
    __syncthreads();
  }

  float bc[2];
#pragma unroll
  for (int ni = 0; ni < 2; ni++) bc[ni] = bias[n0 + wc * 32 + ni * 16 + arow];
#pragma unroll
  for (int mi = 0; mi < 4; mi++)
#pragma unroll
    for (int ni = 0; ni < 2; ni++)
#pragma unroll
      for (int j = 0; j < 4; j++) {
        int row = m0 + wr * 64 + mi * 16 + (lane >> 4) * 4 + j;
        int col = n0 + wc * 32 + ni * 16 + arow;
        int qv = __float2int_rn((acc[mi][ni][j] + bc[ni]) * QSCALE);
        qv = qv > 127 ? 127 : (qv < -127 ? -127 : qv);
        Out[(size_t)row * DN + col] = (signed char)qv;
      }
}

// ---------------------------------------------------------------------------
// Pairwise logits + fused max/sum reductions, INT8 with exact i32 accumulation.
// == round-14 version, byte-identical ==
__global__ __launch_bounds__(512, 2) void pairs_kernel(const signed char* __restrict__ Q,
                                                       const signed char* __restrict__ Km,
                                                       const float* __restrict__ amask,
                                                       const float* __restrict__ ls_ptr,
                                                       float* __restrict__ out) {
  __shared__ __align__(16) signed char lds[2 * 2 * 256 * 128];  // 128 KiB
  const int tid = threadIdx.x;
  const int wave = tid >> 6, lane = tid & 63;
  const int wr = wave >> 2, wc = wave & 3;
  const int arow = lane & 15, g = lane >> 4;

  const int bid = blockIdx.x;
  const int gen = bid >> 8, slot = bid & 255;
  const int xcd = slot & 7, idx = slot >> 3;
  const int by = ((gen & 1) << 4) + ((xcd >> 1) << 2) + (idx >> 3);
  const int bx = ((gen >> 1) << 4) + ((xcd & 1) << 3) + (idx & 7);

  const int l8 = lane >> 3, l7 = lane & 7;
  const int srcSlot = l7 ^ l8;

  // epilogue scalars first; drain their vmem so pipeline vmcnt counts are exact
  const float lsv = expf(ls_ptr[0]);
  float am2[2];
#pragma unroll
  for (int ph = 0; ph < 2; ph++) {
    float am = amask[(by * 4 + wr * 2 + ph) * 64 + lane];
#pragma unroll
    for (int off = 1; off < 64; off <<= 1) am += __shfl_xor(am, off);
    am2[ph] = am;
  }
  VMC(0); SCHED0();

  i32x4 acc[8][4] = {};
  i32x4 aA[4], aB[4], bR0[4], bR1[4];

  // stage A unit u (u0: rows 0-63 & 128-191; u1: rows 64-127 & 192-255)
  auto SA = [&](int u, int k, int d) {
    int base = (wave >> 2) * 128 + u * 64 + (wave & 3) * 16;
#pragma unroll
    for (int i = 0; i < 2; i++) {
      int row = base + i * 8;
      GLL16(Q + (size_t)(by * 256 + row + l8) * DN + k * 128 + srcSlot * 16,
            &lds[(d * 2 + 0) * 32768 + row * 128]);
    }
  };
  auto SB = [&](int half, int k, int d) {
#pragma unroll
    for (int i = 0; i < 2; i++) {
      int row = half * 128 + wave * 16 + i * 8;
      GLL16(Km + (size_t)(bx * 256 + row + l8) * DN + k * 128 + srcSlot * 16,
            &lds[(d * 2 + 1) * 32768 + row * 128]);
    }
  };
  auto LDA = [&](i32x4* ar, int mh, int ks, int d) {
#pragma unroll
    for (int mi = 0; mi < 4; mi++) {
      int row = wr * 128 + (mh * 4 + mi) * 16 + arow;
      int slt = ((ks << 2) | g) ^ (arow & 7);
      ar[mi] = *(const i32x4*)&lds[(d * 2 + 0) * 32768 + row * 128 + slt * 16];
    }
  };
  auto LDB = [&](i32x4* br, int ks, int d) {
#pragma unroll
    for (int ni = 0; ni < 4; ni++) {
      int row = wc * 64 + ni * 16 + arow;
      int slt = ((ks << 2) | g) ^ (arow & 7);
      br[ni] = *(const i32x4*)&lds[(d * 2 + 1) * 32768 + row * 128 + slt * 16];
    }
  };
  auto MMA = [&](int mh, i32x4* ar, i32x4* br) {
    __builtin_amdgcn_s_setprio(1);
#pragma unroll
    for (int mi = 0; mi < 4; mi++)
#pragma unroll
      for (int ni = 0; ni < 4; ni++)
        acc[mh * 4 + mi][ni] = __builtin_amdgcn_mfma_i32_16x16x64_i8(
            ar[mi], br[ni], acc[mh * 4 + mi][ni], 0, 0, 0);
    __builtin_amdgcn_s_setprio(0);
  };

  // prologue: stage tile 0 fully; wait {B-lo,B-hi,A-u0}, leave A-u1 in flight
  SB(0, 0, 0); SB(1, 0, 0); SA(0, 0, 0); SA(1, 0, 0);
  VMC(2);
  BAR(); SCHED0();

#pragma unroll
  for (int k = 0; k < 4; ++k) {
    const int d = k & 1, dn = d ^ 1;
    const bool doST = (k < 3);
    // issue next tile's 8 stage loads first (issue-early, land-late)
    if (doST) { SB(0, k + 1, dn); SB(1, k + 1, dn); SA(0, k + 1, dn); SA(1, k + 1, dn); }
    LDB(bR0, 0, d); LDB(bR1, 1, d);
    LDA(aA, 0, 0, d); MMA(0, aA, bR0);
    LDA(aB, 0, 1, d); MMA(0, aB, bR1);
    // A-u1 of THIS tile was left in flight: validate (waits 2 oldest)
    if (doST) { VMC(8); } else { VMC(0); }
    BAR();
    LDA(aA, 1, 0, d); MMA(1, aA, bR0);
    LDA(aB, 1, 1, d); MMA(1, aB, bR1);
    // boundary: next tile's {B-lo,B-hi,A-u0} done, leave its A-u1 in flight
    if (doST) { VMC(2); }
    BAR(); SCHED0();
  }

  // ---- fused epilogue: two (a,b) pairs per wave ----
  // C/D layout (dtype-independent): col = lane&15, row = (lane>>4)*4 + reg.
  // Maxes on raw int-as-float (monotone); scale by 1/s^2 at the end.
#pragma unroll
  for (int ph = 0; ph < 2; ph++) {
    float t2v = 0.f;
#pragma unroll
    for (int mi = ph * 4; mi < ph * 4 + 4; mi++) {
      f32x4 rm;
#pragma unroll
      for (int j = 0; j < 4; j++) rm[j] = (float)acc[mi][0][j];
#pragma unroll
      for (int ni = 1; ni < 4; ni++)
#pragma unroll
        for (int j = 0; j < 4; j++) rm[j] = fmaxf(rm[j], (float)acc[mi][ni][j]);
#pragma unroll
      for (int off = 1; off < 16; off <<= 1)
#pragma unroll
        for (int j = 0; j < 4; j++) rm[j] = fmaxf(rm[j], __shfl_xor(rm[j], off));
      t2v += rm[0] + rm[1] + rm[2] + rm[3];
    }
    t2v += __shfl_xor(t2v, 16);
    t2v += __shfl_xor(t2v, 32);

    float v2t = 0.f;
#pragma unroll
    for (int ni = 0; ni < 4; ni++) {
      float cm = -INFINITY;
#pragma unroll
      for (int mi = ph * 4; mi < ph * 4 + 4; mi++)
#pragma unroll
        for (int j = 0; j < 4; j++) cm = fmaxf(cm, (float)acc[mi][ni][j]);
      cm = fmaxf(cm, __shfl_xor(cm, 16));
      cm = fmaxf(cm, __shfl_xor(cm, 32));
      v2t += cm;
    }
#pragma unroll
    for (int off = 1; off < 16; off <<= 1) v2t += __shfl_xor(v2t, off);

    const int a = by * 4 + wr * 2 + ph, b = bx * 4 + wc;
    float r = lsv * 0.5f * ((t2v * QINVS2) / am2[ph] + (v2t * QINVS2) / 64.0f);
    if (lane == 0) {
      out[a * NB + b] = r;                 // r
      out[NB * NB + b * NB + a] = r;       // r.T
    }
  }
}

// ---------------------------------------------------------------------------
extern "C" void kernel_launch(void* const* d_in, const int* in_sizes, int n_in,
                              void* d_out, int out_size, void* d_ws, size_t ws_size,
                              hipStream_t stream) {
  const float* query = (const float*)d_in[0];
  const float* key   = (const float*)d_in[1];
  const float* amask = (const float*)d_in[2];
  const float* Wq    = (const float*)d_in[3];
  const float* bq    = (const float*)d_in[4];
  const float* Wk    = (const float*)d_in[5];
  const float* bk    = (const float*)d_in[6];
  const float* ls    = (const float*)d_in[7];

  char* ws = (char*)d_ws;
  signed char* Qb = (signed char*)(ws);                      // 4 MB
  signed char* Kb = (signed char*)(ws + 4 * 1024 * 1024);    // 4 MB

  proj_kernel<<<dim3(1024), 256, 0, stream>>>(query, Wq, bq, Qb, key, Wk, bk, Kb);
  pairs_kernel<<<dim3(1024), 512, 0, stream>>>(Qb, Kb, amask, ls, (float*)d_out);
}

// Round 18
// 69.209 us; speedup vs baseline: 1.0637x; 1.0637x over previous
//
#include <hip/hip_runtime.h>
#include <math.h>

// Problem constants: N=128, LQ=LK=64, D=512, H=8 (head split is a no-op in the einsum).
#define DN 512          // feature dim
#define NB 128          // batch N
#define QSCALE 25.0f
#define QINVS2 (1.0f / (QSCALE * QSCALE))

typedef unsigned short ushort_t;
typedef __attribute__((ext_vector_type(8))) short bf16x8;
typedef __attribute__((ext_vector_type(4))) float f32x4;
typedef __attribute__((ext_vector_type(4))) int i32x4;

static __device__ __forceinline__ ushort_t f2bf(float f){
  unsigned u = __float_as_uint(f);
  u += 0x7fffu + ((u >> 16) & 1u);   // round-to-nearest-even
  return (ushort_t)(u >> 16);
}

// async global->LDS, 16B per lane; LDS dest is wave-uniform base + lane*16
#define GLL16(gp, lp)                                                          \
  __builtin_amdgcn_global_load_lds(                                            \
      (const __attribute__((address_space(1))) void*)(gp),                     \
      (__attribute__((address_space(3))) void*)(lp), 16, 0, 0)

#define BAR() __builtin_amdgcn_s_barrier()
#define SCHED0() __builtin_amdgcn_sched_barrier(0)
#define VMC(N)                                                                 \
  do {                                                                         \
    asm volatile("s_waitcnt vmcnt(" #N ")" ::: "memory");                      \
  } while (0)

// ---------------------------------------------------------------------------
// Projections (both Q and K in one launch). Out = X @ W^T + bias, 128x128
// tile, BK=64, 4 waves, LDS 16B-slot XOR swizzle (slot ^= row&7). Block
// decode groups the 4 n-blocks sharing an X m-tile onto the same XCD (r12).
// Epilogue quantizes to int8: round(clamp(v)*25), exact-int pairs GEMM input.
// == round-14 champion, byte-identical ==
__global__ __launch_bounds__(256) void proj_kernel(const float* __restrict__ Xq,
                                                   const float* __restrict__ Wq,
                                                   const float* __restrict__ bq,
                                                   signed char* __restrict__ Oq,
                                                   const float* __restrict__ Xk,
                                                   const float* __restrict__ Wk,
                                                   const float* __restrict__ bk,
                                                   signed char* __restrict__ Ok) {
  const int fid = blockIdx.x;                  // 0..511
  const int xcd = fid & 7, local = fid >> 3;   // 64 locals per XCD
  const int mt = xcd * 8 + (local & 7);        // 0..63 (m-tile)
  const int nt = (local >> 3) & 3;             // 0..3  (n-tile)
  const int zz = local >> 5;                   // 0 = Q, 1 = K

  const float* X = zz ? Xk : Xq;
  const float* W = zz ? Wk : Wq;
  const float* bias = zz ? bk : bq;
  signed char* Out = zz ? Ok : Oq;

  __shared__ __align__(16) ushort_t As[128 * 64];
  __shared__ __align__(16) ushort_t Bs[128 * 64];
  const int tid = threadIdx.x;
  const int wave = tid >> 6, lane = tid & 63;
  const int wr = wave >> 1, wc = wave & 1;
  const int m0 = mt * 128, n0 = nt * 128;
  const int arow = lane & 15, g = lane >> 4;

  f32x4 acc[4][4] = {};

  for (int kt = 0; kt < 8; ++kt) {
    const int k0 = kt * 64;
#pragma unroll
    for (int i = 0; i < 8; i++) {
      int e = i * 1024 + tid * 4;
      int r = e >> 6, c = e & 63;
      int cs = ((((c >> 3) ^ (r & 7)) << 3) | (c & 7));
      float4 va = *(const float4*)&X[(size_t)(m0 + r) * DN + k0 + c];
      ushort4 ha;
      ha.x = f2bf(va.x); ha.y = f2bf(va.y); ha.z = f2bf(va.z); ha.w = f2bf(va.w);
      *(ushort4*)&As[r * 64 + cs] = ha;
      float4 vb = *(const float4*)&W[(size_t)(n0 + r) * DN + k0 + c];
      ushort4 hb;
      hb.x = f2bf(vb.x); hb.y = f2bf(vb.y); hb.z = f2bf(vb.z); hb.w = f2bf(vb.w);
      *(ushort4*)&Bs[r * 64 + cs] = hb;
    }
    __syncthreads();

    bf16x8 af[4][2], bfr[4][2];
#pragma unroll
    for (int mi = 0; mi < 4; mi++)
#pragma unroll
      for (int ks = 0; ks < 2; ks++)
        af[mi][ks] = *(const bf16x8*)&As[(wr * 64 + mi * 16 + arow) * 64 +
                                         ((((ks << 2) | g) ^ (arow & 7)) << 3)];
#pragma unroll
    for (int ni = 0; ni < 4; ni++)
#pragma unroll
      for (int ks = 0; ks < 2; ks++)
        bfr[ni][ks] = *(const bf16x8*)&Bs[(wc * 64 + ni * 16 + arow) * 64 +
                                          ((((ks << 2) | g) ^ (arow & 7)) << 3)];
#pragma unroll
    for (int ks = 0; ks < 2; ks++)
#pragma unroll
      for (int mi = 0; mi < 4; mi++)
#pragma unroll
        for (int ni = 0; ni < 4; ni++)
          acc[mi][ni] = __builtin_amdgcn_mfma_f32_16x16x32_bf16(
              af[mi][ks], bfr[ni][ks], acc[mi][ni], 0, 0, 0);
    __syncthreads();
  }

  float bc[4];
#pragma unroll
  for (int ni = 0; ni < 4; ni++) bc[ni] = bias[n0 + wc * 64 + ni * 16 + arow];
#pragma unroll
  for (int mi = 0; mi < 4; mi++)
#pragma unroll
    for (int ni = 0; ni < 4; ni++)
#pragma unroll
      for (int j = 0; j < 4; j++) {
        int row = m0 + wr * 64 + mi * 16 + (lane >> 4) * 4 + j;
        int col = n0 + wc * 64 + ni * 16 + arow;
        int qv = __float2int_rn((acc[mi][ni][j] + bc[ni]) * QSCALE);
        qv = qv > 127 ? 127 : (qv < -127 ? -127 : qv);
        Out[(size_t)row * DN + col] = (signed char)qv;
      }
}

// ---------------------------------------------------------------------------
// Pairwise logits + fused max/sum reductions, INT8 with exact i32 accumulation.
// == round-14 champion, byte-identical ==
__global__ __launch_bounds__(512, 2) void pairs_kernel(const signed char* __restrict__ Q,
                                                       const signed char* __restrict__ Km,
                                                       const float* __restrict__ amask,
                                                       const float* __restrict__ ls_ptr,
                                                       float* __restrict__ out) {
  __shared__ __align__(16) signed char lds[2 * 2 * 256 * 128];  // 128 KiB
  const int tid = threadIdx.x;
  const int wave = tid >> 6, lane = tid & 63;
  const int wr = wave >> 2, wc = wave & 3;
  const int arow = lane & 15, g = lane >> 4;

  const int bid = blockIdx.x;
  const int gen = bid >> 8, slot = bid & 255;
  const int xcd = slot & 7, idx = slot >> 3;
  const int by = ((gen & 1) << 4) + ((xcd >> 1) << 2) + (idx >> 3);
  const int bx = ((gen >> 1) << 4) + ((xcd & 1) << 3) + (idx & 7);

  const int l8 = lane >> 3, l7 = lane & 7;
  const int srcSlot = l7 ^ l8;

  // epilogue scalars first; drain their vmem so pipeline vmcnt counts are exact
  const float lsv = expf(ls_ptr[0]);
  float am2[2];
#pragma unroll
  for (int ph = 0; ph < 2; ph++) {
    float am = amask[(by * 4 + wr * 2 + ph) * 64 + lane];
#pragma unroll
    for (int off = 1; off < 64; off <<= 1) am += __shfl_xor(am, off);
    am2[ph] = am;
  }
  VMC(0); SCHED0();

  i32x4 acc[8][4] = {};
  i32x4 aA[4], aB[4], bR0[4], bR1[4];

  // stage A unit u (u0: rows 0-63 & 128-191; u1: rows 64-127 & 192-255)
  auto SA = [&](int u, int k, int d) {
    int base = (wave >> 2) * 128 + u * 64 + (wave & 3) * 16;
#pragma unroll
    for (int i = 0; i < 2; i++) {
      int row = base + i * 8;
      GLL16(Q + (size_t)(by * 256 + row + l8) * DN + k * 128 + srcSlot * 16,
            &lds[(d * 2 + 0) * 32768 + row * 128]);
    }
  };
  auto SB = [&](int half, int k, int d) {
#pragma unroll
    for (int i = 0; i < 2; i++) {
      int row = half * 128 + wave * 16 + i * 8;
      GLL16(Km + (size_t)(bx * 256 + row + l8) * DN + k * 128 + srcSlot * 16,
            &lds[(d * 2 + 1) * 32768 + row * 128]);
    }
  };
  auto LDA = [&](i32x4* ar, int mh, int ks, int d) {
#pragma unroll
    for (int mi = 0; mi < 4; mi++) {
      int row = wr * 128 + (mh * 4 + mi) * 16 + arow;
      int slt = ((ks << 2) | g) ^ (arow & 7);
      ar[mi] = *(const i32x4*)&lds[(d * 2 + 0) * 32768 + row * 128 + slt * 16];
    }
  };
  auto LDB = [&](i32x4* br, int ks, int d) {
#pragma unroll
    for (int ni = 0; ni < 4; ni++) {
      int row = wc * 64 + ni * 16 + arow;
      int slt = ((ks << 2) | g) ^ (arow & 7);
      br[ni] = *(const i32x4*)&lds[(d * 2 + 1) * 32768 + row * 128 + slt * 16];
    }
  };
  auto MMA = [&](int mh, i32x4* ar, i32x4* br) {
    __builtin_amdgcn_s_setprio(1);
#pragma unroll
    for (int mi = 0; mi < 4; mi++)
#pragma unroll
      for (int ni = 0; ni < 4; ni++)
        acc[mh * 4 + mi][ni] = __builtin_amdgcn_mfma_i32_16x16x64_i8(
            ar[mi], br[ni], acc[mh * 4 + mi][ni], 0, 0, 0);
    __builtin_amdgcn_s_setprio(0);
  };

  // prologue: stage tile 0 fully; wait {B-lo,B-hi,A-u0}, leave A-u1 in flight
  SB(0, 0, 0); SB(1, 0, 0); SA(0, 0, 0); SA(1, 0, 0);
  VMC(2);
  BAR(); SCHED0();

#pragma unroll
  for (int k = 0; k < 4; ++k) {
    const int d = k & 1, dn = d ^ 1;
    const bool doST = (k < 3);
    // issue next tile's 8 stage loads first (issue-early, land-late)
    if (doST) { SB(0, k + 1, dn); SB(1, k + 1, dn); SA(0, k + 1, dn); SA(1, k + 1, dn); }
    LDB(bR0, 0, d); LDB(bR1, 1, d);
    LDA(aA, 0, 0, d); MMA(0, aA, bR0);
    LDA(aB, 0, 1, d); MMA(0, aB, bR1);
    // A-u1 of THIS tile was left in flight: validate (waits 2 oldest)
    if (doST) { VMC(8); } else { VMC(0); }
    BAR();
    LDA(aA, 1, 0, d); MMA(1, aA, bR0);
    LDA(aB, 1, 1, d); MMA(1, aB, bR1);
    // boundary: next tile's {B-lo,B-hi,A-u0} done, leave its A-u1 in flight
    if (doST) { VMC(2); }
    BAR(); SCHED0();
  }

  // ---- fused epilogue: two (a,b) pairs per wave ----
  // C/D layout (dtype-independent): col = lane&15, row = (lane>>4)*4 + reg.
  // Maxes on raw int-as-float (monotone); scale by 1/s^2 at the end.
#pragma unroll
  for (int ph = 0; ph < 2; ph++) {
    float t2v = 0.f;
#pragma unroll
    for (int mi = ph * 4; mi < ph * 4 + 4; mi++) {
      f32x4 rm;
#pragma unroll
      for (int j = 0; j < 4; j++) rm[j] = (float)acc[mi][0][j];
#pragma unroll
      for (int ni = 1; ni < 4; ni++)
#pragma unroll
        for (int j = 0; j < 4; j++) rm[j] = fmaxf(rm[j], (float)acc[mi][ni][j]);
#pragma unroll
      for (int off = 1; off < 16; off <<= 1)
#pragma unroll
        for (int j = 0; j < 4; j++) rm[j] = fmaxf(rm[j], __shfl_xor(rm[j], off));
      t2v += rm[0] + rm[1] + rm[2] + rm[3];
    }
    t2v += __shfl_xor(t2v, 16);
    t2v += __shfl_xor(t2v, 32);

    float v2t = 0.f;
#pragma unroll
    for (int ni = 0; ni < 4; ni++) {
      float cm = -INFINITY;
#pragma unroll
      for (int mi = ph * 4; mi < ph * 4 + 4; mi++)
#pragma unroll
        for (int j = 0; j < 4; j++) cm = fmaxf(cm, (float)acc[mi][ni][j]);
      cm = fmaxf(cm, __shfl_xor(cm, 16));
      cm = fmaxf(cm, __shfl_xor(cm, 32));
      v2t += cm;
    }
#pragma unroll
    for (int off = 1; off < 16; off <<= 1) v2t += __shfl_xor(v2t, off);

    const int a = by * 4 + wr * 2 + ph, b = bx * 4 + wc;
    float r = lsv * 0.5f * ((t2v * QINVS2) / am2[ph] + (v2t * QINVS2) / 64.0f);
    if (lane == 0) {
      out[a * NB + b] = r;                 // r
      out[NB * NB + b * NB + a] = r;       // r.T
    }
  }
}

// ---------------------------------------------------------------------------
extern "C" void kernel_launch(void* const* d_in, const int* in_sizes, int n_in,
                              void* d_out, int out_size, void* d_ws, size_t ws_size,
                              hipStream_t stream) {
  const float* query = (const float*)d_in[0];
  const float* key   = (const float*)d_in[1];
  const float* amask = (const float*)d_in[2];
  const float* Wq    = (const float*)d_in[3];
  const float* bq    = (const float*)d_in[4];
  const float* Wk    = (const float*)d_in[5];
  const float* bk    = (const float*)d_in[6];
  const float* ls    = (const float*)d_in[7];

  char* ws = (char*)d_ws;
  signed char* Qb = (signed char*)(ws);                      // 4 MB
  signed char* Kb = (signed char*)(ws + 4 * 1024 * 1024);    // 4 MB

  proj_kernel<<<dim3(512), 256, 0, stream>>>(query, Wq, bq, Qb, key, Wk, bk, Kb);
  pairs_kernel<<<dim3(1024), 512, 0, stream>>>(Qb, Kb, amask, ls, (float*)d_out);
}